// Round 2
// baseline (764.208 us; speedup 1.0000x reference)
//
#include <hip/hip_runtime.h>

// Antialiased bilinear downsample (JAX triangle filter, scale=1/4 both axes):
//   in  (2048, 6, 128, 96) fp32 -> out (2048, 6, 32, 24) fp32
// Separable 8-tap filter. Interior weights [1,3,5,7,7,5,3,1]/32; edge outputs
// (o==0 / o==last) zero 2 OOB taps and renormalize by 3.5.
//
// R2 structure: vertical pass global->registers (float4 columns, coalesced),
// 12.8 KB LDS intermediate only, ONE barrier, 4 blocks/CU.

#define IMG_H 128
#define IMG_W 96      // = 24 float4 chunks per row
#define OH 32
#define OW 24
#define TSTR 100      // tmp row stride in floats (16B-aligned, breaks pow2 banks)

__global__ __launch_bounds__(256, 4)
void resize_aa_kernel(const float* __restrict__ x, float* __restrict__ out) {
    __shared__ float s_tmp[OH * TSTR];   // 12.8 KB

    const int img = blockIdx.x;
    const int tid = threadIdx.x;
    const float4* __restrict__ src4 = (const float4*)(x + (size_t)img * (IMG_H * IMG_W));

    // ---- Vertical pass: tmp[oh][iw] = sum_t wv[t] * in[4oh-2+t][iw] ----
    // 768 float4 column-entries, 3 per thread. Lanes run over c fast ->
    // 384 B contiguous global segments per load instruction.
#pragma unroll
    for (int k = 0; k < 3; ++k) {
        int idx = tid + k * 256;        // 0..767
        int oh = idx / OW;
        int c  = idx - oh * OW;
        int r0 = 4 * oh - 2;

        float w[8] = {1.f/32, 3.f/32, 5.f/32, 7.f/32, 7.f/32, 5.f/32, 3.f/32, 1.f/32};
        if (oh == 0) {
            const float s = 1.0f / 3.5f;
            w[0] = 0.f;        w[1] = 0.f;
            w[2] = 0.625f * s; w[3] = 0.875f * s; w[4] = 0.875f * s;
            w[5] = 0.625f * s; w[6] = 0.375f * s; w[7] = 0.125f * s;
        } else if (oh == OH - 1) {
            const float s = 1.0f / 3.5f;
            w[0] = 0.125f * s; w[1] = 0.375f * s; w[2] = 0.625f * s;
            w[3] = 0.875f * s; w[4] = 0.875f * s; w[5] = 0.625f * s;
            w[6] = 0.f;        w[7] = 0.f;
        }

        float4 v[8];
#pragma unroll
        for (int t = 0; t < 8; ++t) {
            int r = r0 + t;
            r = r < 0 ? 0 : (r > IMG_H - 1 ? IMG_H - 1 : r);  // clamp; w==0 on OOB taps
            v[t] = src4[r * (IMG_W / 4) + c];
        }
        float4 acc = make_float4(0.f, 0.f, 0.f, 0.f);
#pragma unroll
        for (int t = 0; t < 8; ++t) {
            acc.x += w[t] * v[t].x;
            acc.y += w[t] * v[t].y;
            acc.z += w[t] * v[t].z;
            acc.w += w[t] * v[t].w;
        }
        *(float4*)&s_tmp[oh * TSTR + 4 * c] = acc;
    }
    __syncthreads();

    // ---- Horizontal pass: out[oh][ow] = sum_t wh[t] * tmp[oh][4ow-2+t] ----
    float* __restrict__ dst = out + (size_t)img * (OH * OW);
#pragma unroll
    for (int k = 0; k < 3; ++k) {
        int idx = tid + k * 256;        // 0..767
        int oh = idx / OW;
        int ow = idx - oh * OW;
        int c0 = 4 * ow - 2;

        float w[8] = {1.f/32, 3.f/32, 5.f/32, 7.f/32, 7.f/32, 5.f/32, 3.f/32, 1.f/32};
        if (ow == 0) {
            const float s = 1.0f / 3.5f;
            w[0] = 0.f;        w[1] = 0.f;
            w[2] = 0.625f * s; w[3] = 0.875f * s; w[4] = 0.875f * s;
            w[5] = 0.625f * s; w[6] = 0.375f * s; w[7] = 0.125f * s;
        } else if (ow == OW - 1) {
            const float s = 1.0f / 3.5f;
            w[0] = 0.125f * s; w[1] = 0.375f * s; w[2] = 0.625f * s;
            w[3] = 0.875f * s; w[4] = 0.875f * s; w[5] = 0.625f * s;
            w[6] = 0.f;        w[7] = 0.f;
        }

        float acc = 0.f;
#pragma unroll
        for (int t = 0; t < 8; ++t) {
            int cc = c0 + t;
            cc = cc < 0 ? 0 : (cc > IMG_W - 1 ? IMG_W - 1 : cc);  // clamp; w==0 on OOB
            acc += w[t] * s_tmp[oh * TSTR + cc];
        }
        dst[idx] = acc;
    }
}

extern "C" void kernel_launch(void* const* d_in, const int* in_sizes, int n_in,
                              void* d_out, int out_size, void* d_ws, size_t ws_size,
                              hipStream_t stream) {
    const float* x = (const float*)d_in[0];   // (2048, 6, 128, 96) fp32
    // d_in[1] (y) is unused by the forward pass.
    float* out = (float*)d_out;               // (2048*6*768,) fp32
    const int n_img = 2048 * 6;
    resize_aa_kernel<<<n_img, 256, 0, stream>>>(x, out);
}